// Round 2
// baseline (699.044 us; speedup 1.0000x reference)
//
#include <hip/hip_runtime.h>
#include <hip/hip_bf16.h>
#include <cstdint>

// MoE SwiGLU MLP, routed top-2. Round 2: one-shot weight convert+transpose
// pre-pass into LDS-image-tiled bf16, then m97-style GEMMs with
// global_load_lds width-16 (no VALU converts in the K-loop).

typedef short short8 __attribute__((ext_vector_type(8)));
typedef float floatx4 __attribute__((ext_vector_type(4)));

#define H_DIM 1024
#define F_DIM 4096
#define N_EXP 8
#define T_TOK 2048
#define MCAP  5120

#define BM 128
#define BN 64
#define BK 32
#define LDT 40   // fallback-path LDS pitch

struct Meta {
  int cnt[N_EXP];
  int cursor[N_EXP];
  int poff[N_EXP + 1];
  int pad0;
  int pair_token[MCAP];
  float pair_w[MCAP];
  int token_pair[2 * T_TOK];
  int tok_e[2 * T_TOK];
  float tok_w[2 * T_TOK];
};

__device__ __forceinline__ unsigned short f2b(float f) {
  unsigned int u = __float_as_uint(f);
  u = (u + 0x7fffu + ((u >> 16) & 1u)) >> 16;   // RNE
  return (unsigned short)u;
}
__device__ __forceinline__ float b2f(unsigned short h) {
  return __uint_as_float(((unsigned int)h) << 16);
}

// async global->LDS, 16B per lane. lds base must be wave-uniform;
// data lands at base + lane*16 (m97/m104 semantics).
__device__ __forceinline__ void gll16(const void* g, void* l) {
  __builtin_amdgcn_global_load_lds(
      (const __attribute__((address_space(1))) unsigned int*)g,
      (__attribute__((address_space(3))) unsigned int*)l, 16, 0, 0);
}

__global__ void k_init(Meta* __restrict__ m) {
  int i = threadIdx.x;
  if (i < N_EXP) { m->cnt[i] = 0; m->cursor[i] = 0; }
}

__global__ __launch_bounds__(64)
void k_router(const float* __restrict__ x, const float* __restrict__ gw,
              Meta* __restrict__ m) {
  int t = blockIdx.x;
  int lane = threadIdx.x;
  const float* xr = x + (size_t)t * H_DIM;
  float acc[N_EXP];
#pragma unroll
  for (int e = 0; e < N_EXP; ++e) acc[e] = 0.f;
  for (int i = 0; i < H_DIM / 64; ++i) {
    int h = i * 64 + lane;
    float xv = xr[h];
    const float* g = gw + (size_t)h * N_EXP;
#pragma unroll
    for (int e = 0; e < N_EXP; ++e) acc[e] += xv * g[e];
  }
#pragma unroll
  for (int e = 0; e < N_EXP; ++e) {
    float v = acc[e];
    for (int off = 32; off; off >>= 1) v += __shfl_xor(v, off, 64);
    acc[e] = v;
  }
  if (lane == 0) {
    float mx = acc[0];
    for (int e = 1; e < N_EXP; ++e) mx = fmaxf(mx, acc[e]);
    float p[N_EXP];
    float s = 0.f;
    for (int e = 0; e < N_EXP; ++e) { p[e] = __expf(acc[e] - mx); s += p[e]; }
    float inv = 1.f / s;
    for (int e = 0; e < N_EXP; ++e) p[e] *= inv;
    int i1 = 0;
    for (int e = 1; e < N_EXP; ++e) if (p[e] > p[i1]) i1 = e;
    int i2 = (i1 == 0) ? 1 : 0;
    for (int e = 0; e < N_EXP; ++e) if (e != i1 && p[e] > p[i2]) i2 = e;
    float w1 = 1.f / (1.f + __expf(p[i2] - p[i1]));  // softmax of top-2 probs
    m->tok_e[2 * t] = i1;     m->tok_e[2 * t + 1] = i2;
    m->tok_w[2 * t] = w1;     m->tok_w[2 * t + 1] = 1.f - w1;
    atomicAdd(&m->cnt[i1], 1);
    atomicAdd(&m->cnt[i2], 1);
  }
}

__global__ void k_scan(Meta* __restrict__ m) {
  if (threadIdx.x == 0 && blockIdx.x == 0) {
    int o = 0;
    for (int e = 0; e < N_EXP; ++e) {
      m->poff[e] = o;
      o += ((m->cnt[e] + BM - 1) / BM) * BM;
    }
    m->poff[N_EXP] = o;
  }
}

__global__ void k_assign(Meta* __restrict__ m) {
  int t = blockIdx.x * blockDim.x + threadIdx.x;
  if (t >= T_TOK) return;
  for (int k = 0; k < 2; ++k) {
    int e = m->tok_e[2 * t + k];
    int idx = atomicAdd(&m->cursor[e], 1);
    int p = m->poff[e] + idx;
    m->pair_token[p] = t;
    m->pair_w[p] = m->tok_w[2 * t + k];
    m->token_pair[2 * t + k] = p;
  }
}

__global__ __launch_bounds__(256)
void k_gather(const float* __restrict__ x, unsigned short* __restrict__ Xe,
              const Meta* __restrict__ m) {
  int r = blockIdx.x;
  if (r >= m->poff[N_EXP]) return;
  int e = 0;
#pragma unroll
  for (int i = 1; i < N_EXP; ++i) if (r >= m->poff[i]) e = i;
  bool real = (r - m->poff[e]) < m->cnt[e];
  int h = threadIdx.x * 4;
  ushort4 sv = {0, 0, 0, 0};
  if (real) {
    int t = m->pair_token[r];
    float4 f = *(const float4*)(x + (size_t)t * H_DIM + h);
    sv.x = f2b(f.x); sv.y = f2b(f.y); sv.z = f2b(f.z); sv.w = f2b(f.w);
  }
  *(ushort4*)(Xe + (size_t)r * H_DIM + h) = sv;
}

// ---------------- pre-pass: fp32 [e][K][N] -> bf16 tiled [e][nt][kb][2048] ----------------
// Tile image: element (n,k) at n*32+k (n in [0,64), k in [0,32)) == linear
// 16B-chunk order for global_load_lds. Block 256 thr, one (e, ntile) column,
// 32 k-blocks per grid.z slab.
__global__ __launch_bounds__(256)
void k_prep(const float* __restrict__ W, unsigned short* __restrict__ Wt,
            int K, int NT, int N) {
  __shared__ __align__(16) unsigned short Ls[2048];
  int e = blockIdx.y, nt = blockIdx.x;
  int t = threadIdx.x;
  int KB = K >> 5;
  int kb0 = blockIdx.z * 32;
  int kb1 = kb0 + 32;
  int k = t >> 3;            // 0..31
  int nc = (t & 7) * 8;      // 0,8,..,56
  for (int kb = kb0; kb < kb1; ++kb) {
    const float* src = W + ((size_t)e * K + (size_t)kb * 32 + k) * N + (size_t)nt * 64 + nc;
    float4 f0 = *(const float4*)src;
    float4 f1 = *(const float4*)(src + 4);
    Ls[(nc + 0) * 32 + k] = f2b(f0.x);
    Ls[(nc + 1) * 32 + k] = f2b(f0.y);
    Ls[(nc + 2) * 32 + k] = f2b(f0.z);
    Ls[(nc + 3) * 32 + k] = f2b(f0.w);
    Ls[(nc + 4) * 32 + k] = f2b(f1.x);
    Ls[(nc + 5) * 32 + k] = f2b(f1.y);
    Ls[(nc + 6) * 32 + k] = f2b(f1.z);
    Ls[(nc + 7) * 32 + k] = f2b(f1.w);
    __syncthreads();
    short8 v = *(const short8*)&Ls[t * 8];
    size_t dst = (((size_t)e * NT + nt) * KB + kb) * 2048 + (size_t)t * 8;
    *(short8*)&Wt[dst] = v;
    __syncthreads();
  }
}

// ---------------- new GEMMs: global_load_lds staging, bf16 tiled B ----------------
__global__ __launch_bounds__(256, 2)
void k_gemm_dual2(const unsigned short* __restrict__ Xe,
                  const unsigned short* __restrict__ WtG,
                  const unsigned short* __restrict__ WtU,
                  unsigned short* __restrict__ Aw,
                  const Meta* __restrict__ m) {
  __shared__ __align__(16) unsigned short As[BM * 32];
  __shared__ __align__(16) unsigned short Bg[BN * 32];
  __shared__ __align__(16) unsigned short Bu[BN * 32];
  int tileM = blockIdx.y * BM;
  if (tileM >= m->poff[N_EXP]) return;
  int e = 0;
#pragma unroll
  for (int i = 1; i < N_EXP; ++i) if (tileM >= m->poff[i]) e = i;
  int nt = blockIdx.x;
  int n0 = nt * BN;

  int tid = threadIdx.x;
  int lane = tid & 63;
  int wid = tid >> 6;
  int wm = (wid & 1) * 64;
  int wn = (wid >> 1) * 32;
  int lm = lane & 15;
  int quad = lane >> 4;

  floatx4 accG[4][2] = {};
  floatx4 accU[4][2] = {};

  int c0 = wid * 128 + lane;       // A chunk ids
  int c1 = c0 + 64;
  int bc = wid * 64 + lane;        // B chunk id

  for (int k0 = 0; k0 < H_DIM; k0 += BK) {
    int kb = k0 >> 5;
    size_t btile = (((size_t)e * (F_DIM / 64) + nt) * (H_DIM / 32) + kb) * 2048;
    gll16(Xe + (size_t)(tileM + (c0 >> 2)) * H_DIM + k0 + (c0 & 3) * 8, &As[wid * 1024]);
    gll16(Xe + (size_t)(tileM + (c1 >> 2)) * H_DIM + k0 + (c1 & 3) * 8, &As[wid * 1024 + 512]);
    gll16(WtG + btile + (size_t)bc * 8, &Bg[wid * 512]);
    gll16(WtU + btile + (size_t)bc * 8, &Bu[wid * 512]);
    __syncthreads();
    short8 a[4];
#pragma unroll
    for (int fm = 0; fm < 4; ++fm)
      a[fm] = *(const short8*)&As[(wm + fm * 16 + lm) * 32 + quad * 8];
#pragma unroll
    for (int fn = 0; fn < 2; ++fn) {
      short8 bg = *(const short8*)&Bg[(wn + fn * 16 + lm) * 32 + quad * 8];
      short8 bu = *(const short8*)&Bu[(wn + fn * 16 + lm) * 32 + quad * 8];
#pragma unroll
      for (int fm = 0; fm < 4; ++fm) {
        accG[fm][fn] = __builtin_amdgcn_mfma_f32_16x16x32_bf16(a[fm], bg, accG[fm][fn], 0, 0, 0);
        accU[fm][fn] = __builtin_amdgcn_mfma_f32_16x16x32_bf16(a[fm], bu, accU[fm][fn], 0, 0, 0);
      }
    }
    __syncthreads();
  }
#pragma unroll
  for (int fm = 0; fm < 4; ++fm)
#pragma unroll
    for (int fn = 0; fn < 2; ++fn)
#pragma unroll
      for (int r = 0; r < 4; ++r) {
        int row = tileM + wm + fm * 16 + quad * 4 + r;
        int col = n0 + wn + fn * 16 + lm;
        float g = accG[fm][fn][r];
        float u = accU[fm][fn][r];
        float s = g / (1.f + __expf(-g));
        Aw[(size_t)row * F_DIM + col] = f2b(s * u);
      }
}

__global__ __launch_bounds__(256, 2)
void k_gemm_down2(const unsigned short* __restrict__ Aw,
                  const unsigned short* __restrict__ WtD,
                  unsigned short* __restrict__ Y,
                  const Meta* __restrict__ m) {
  __shared__ __align__(16) unsigned short As[BM * 32];
  __shared__ __align__(16) unsigned short Bs[BN * 32];
  int tileM = blockIdx.y * BM;
  if (tileM >= m->poff[N_EXP]) return;
  int e = 0;
#pragma unroll
  for (int i = 1; i < N_EXP; ++i) if (tileM >= m->poff[i]) e = i;
  int nt = blockIdx.x;
  int n0 = nt * BN;

  int tid = threadIdx.x;
  int lane = tid & 63;
  int wid = tid >> 6;
  int wm = (wid & 1) * 64;
  int wn = (wid >> 1) * 32;
  int lm = lane & 15;
  int quad = lane >> 4;

  floatx4 acc[4][2] = {};

  int c0 = wid * 128 + lane;
  int c1 = c0 + 64;
  int bc = wid * 64 + lane;

  for (int k0 = 0; k0 < F_DIM; k0 += BK) {
    int kb = k0 >> 5;
    size_t btile = (((size_t)e * (H_DIM / 64) + nt) * (F_DIM / 32) + kb) * 2048;
    gll16(Aw + (size_t)(tileM + (c0 >> 2)) * F_DIM + k0 + (c0 & 3) * 8, &As[wid * 1024]);
    gll16(Aw + (size_t)(tileM + (c1 >> 2)) * F_DIM + k0 + (c1 & 3) * 8, &As[wid * 1024 + 512]);
    gll16(WtD + btile + (size_t)bc * 8, &Bs[wid * 512]);
    __syncthreads();
    short8 a[4];
#pragma unroll
    for (int fm = 0; fm < 4; ++fm)
      a[fm] = *(const short8*)&As[(wm + fm * 16 + lm) * 32 + quad * 8];
#pragma unroll
    for (int fn = 0; fn < 2; ++fn) {
      short8 b = *(const short8*)&Bs[(wn + fn * 16 + lm) * 32 + quad * 8];
#pragma unroll
      for (int fm = 0; fm < 4; ++fm)
        acc[fm][fn] = __builtin_amdgcn_mfma_f32_16x16x32_bf16(a[fm], b, acc[fm][fn], 0, 0, 0);
    }
    __syncthreads();
  }
#pragma unroll
  for (int fm = 0; fm < 4; ++fm)
#pragma unroll
    for (int fn = 0; fn < 2; ++fn)
#pragma unroll
      for (int r = 0; r < 4; ++r) {
        int row = tileM + wm + fm * 16 + quad * 4 + r;
        int col = n0 + wn + fn * 16 + lm;
        Y[(size_t)row * H_DIM + col] = f2b(acc[fm][fn][r]);
      }
}

// ---------------- fallback GEMMs (round-1, fp32 staging) ----------------
__global__ __launch_bounds__(256, 2)
void k_gemm_dual_fb(const unsigned short* __restrict__ Xe,
                    const float* __restrict__ w_gate,
                    const float* __restrict__ w_up,
                    unsigned short* __restrict__ Aw,
                    const Meta* __restrict__ m) {
  __shared__ unsigned short As[BM * LDT];
  __shared__ unsigned short Bg[BN * LDT];
  __shared__ unsigned short Bu[BN * LDT];
  int tileM = blockIdx.y * BM;
  if (tileM >= m->poff[N_EXP]) return;
  int e = 0;
#pragma unroll
  for (int i = 1; i < N_EXP; ++i) if (tileM >= m->poff[i]) e = i;
  int n0 = blockIdx.x * BN;
  const float* Wg = w_gate + (size_t)e * H_DIM * F_DIM;
  const float* Wu = w_up   + (size_t)e * H_DIM * F_DIM;
  int tid = threadIdx.x;
  int lane = tid & 63;
  int wid = tid >> 6;
  int wm = (wid & 1) * 64;
  int wn = (wid >> 1) * 32;
  int lm = lane & 15;
  int quad = lane >> 4;
  floatx4 accG[4][2] = {};
  floatx4 accU[4][2] = {};
  for (int k0 = 0; k0 < H_DIM; k0 += BK) {
    {
      int c = tid;
#pragma unroll
      for (int it = 0; it < 2; ++it, c += 256) {
        int row = c >> 2, kp = c & 3;
        *(uint4*)&As[row * LDT + kp * 8] =
            *(const uint4*)(Xe + (size_t)(tileM + row) * H_DIM + k0 + kp * 8);
      }
    }
    {
      int nn = tid & 63;
      int kh = tid >> 6;
      const float* sg = Wg + (size_t)(k0 + kh * 8) * F_DIM + n0 + nn;
      const float* su = Wu + (size_t)(k0 + kh * 8) * F_DIM + n0 + nn;
      short8 vg, vu;
#pragma unroll
      for (int j = 0; j < 8; ++j) {
        vg[j] = (short)f2b(sg[(size_t)j * F_DIM]);
        vu[j] = (short)f2b(su[(size_t)j * F_DIM]);
      }
      *(short8*)&Bg[nn * LDT + kh * 8] = vg;
      *(short8*)&Bu[nn * LDT + kh * 8] = vu;
    }
    __syncthreads();
    short8 a[4];
#pragma unroll
    for (int fm = 0; fm < 4; ++fm)
      a[fm] = *(const short8*)&As[(wm + fm * 16 + lm) * LDT + quad * 8];
#pragma unroll
    for (int fn = 0; fn < 2; ++fn) {
      short8 bg = *(const short8*)&Bg[(wn + fn * 16 + lm) * LDT + quad * 8];
      short8 bu = *(const short8*)&Bu[(wn + fn * 16 + lm) * LDT + quad * 8];
#pragma unroll
      for (int fm = 0; fm < 4; ++fm) {
        accG[fm][fn] = __builtin_amdgcn_mfma_f32_16x16x32_bf16(a[fm], bg, accG[fm][fn], 0, 0, 0);
        accU[fm][fn] = __builtin_amdgcn_mfma_f32_16x16x32_bf16(a[fm], bu, accU[fm][fn], 0, 0, 0);
      }
    }
    __syncthreads();
  }
#pragma unroll
  for (int fm = 0; fm < 4; ++fm)
#pragma unroll
    for (int fn = 0; fn < 2; ++fn)
#pragma unroll
      for (int r = 0; r < 4; ++r) {
        int row = tileM + wm + fm * 16 + quad * 4 + r;
        int col = n0 + wn + fn * 16 + lm;
        float g = accG[fm][fn][r];
        float u = accU[fm][fn][r];
        float s = g / (1.f + __expf(-g));
        Aw[(size_t)row * F_DIM + col] = f2b(s * u);
      }
}

__global__ __launch_bounds__(256, 2)
void k_gemm_down_fb(const unsigned short* __restrict__ Aw,
                    const float* __restrict__ w_down,
                    unsigned short* __restrict__ Y,
                    const Meta* __restrict__ m) {
  __shared__ unsigned short As[BM * LDT];
  __shared__ unsigned short Bs[BN * LDT];
  int tileM = blockIdx.y * BM;
  if (tileM >= m->poff[N_EXP]) return;
  int e = 0;
#pragma unroll
  for (int i = 1; i < N_EXP; ++i) if (tileM >= m->poff[i]) e = i;
  int n0 = blockIdx.x * BN;
  const float* W = w_down + (size_t)e * F_DIM * H_DIM;
  int tid = threadIdx.x;
  int lane = tid & 63;
  int wid = tid >> 6;
  int wm = (wid & 1) * 64;
  int wn = (wid >> 1) * 32;
  int lm = lane & 15;
  int quad = lane >> 4;
  floatx4 acc[4][2] = {};
  for (int k0 = 0; k0 < F_DIM; k0 += BK) {
    {
      int c = tid;
#pragma unroll
      for (int it = 0; it < 2; ++it, c += 256) {
        int row = c >> 2, kp = c & 3;
        *(uint4*)&As[row * LDT + kp * 8] =
            *(const uint4*)(Aw + (size_t)(tileM + row) * F_DIM + k0 + kp * 8);
      }
    }
    {
      int nn = tid & 63;
      int kh = tid >> 6;
      const float* s = W + (size_t)(k0 + kh * 8) * H_DIM + n0 + nn;
      short8 v;
#pragma unroll
      for (int j = 0; j < 8; ++j) v[j] = (short)f2b(s[(size_t)j * H_DIM]);
      *(short8*)&Bs[nn * LDT + kh * 8] = v;
    }
    __syncthreads();
    short8 a[4];
#pragma unroll
    for (int fm = 0; fm < 4; ++fm)
      a[fm] = *(const short8*)&As[(wm + fm * 16 + lm) * LDT + quad * 8];
#pragma unroll
    for (int fn = 0; fn < 2; ++fn) {
      short8 b = *(const short8*)&Bs[(wn + fn * 16 + lm) * LDT + quad * 8];
#pragma unroll
      for (int fm = 0; fm < 4; ++fm)
        acc[fm][fn] = __builtin_amdgcn_mfma_f32_16x16x32_bf16(a[fm], b, acc[fm][fn], 0, 0, 0);
    }
    __syncthreads();
  }
#pragma unroll
  for (int fm = 0; fm < 4; ++fm)
#pragma unroll
    for (int fn = 0; fn < 2; ++fn)
#pragma unroll
      for (int r = 0; r < 4; ++r) {
        int row = tileM + wm + fm * 16 + quad * 4 + r;
        int col = n0 + wn + fn * 16 + lm;
        Y[(size_t)row * H_DIM + col] = f2b(acc[fm][fn][r]);
      }
}

__global__ __launch_bounds__(256)
void k_combine(const unsigned short* __restrict__ Y, const Meta* __restrict__ m,
               float* __restrict__ out) {
  int t = blockIdx.x;
  int h = threadIdx.x * 4;
  int p0 = m->token_pair[2 * t];
  int p1 = m->token_pair[2 * t + 1];
  float w0 = m->pair_w[p0];
  float w1 = m->pair_w[p1];
  ushort4 y0 = *(const ushort4*)(Y + (size_t)p0 * H_DIM + h);
  ushort4 y1 = *(const ushort4*)(Y + (size_t)p1 * H_DIM + h);
  float4 o;
  o.x = w0 * b2f(y0.x) + w1 * b2f(y1.x);
  o.y = w0 * b2f(y0.y) + w1 * b2f(y1.y);
  o.z = w0 * b2f(y0.z) + w1 * b2f(y1.z);
  o.w = w0 * b2f(y0.w) + w1 * b2f(y1.w);
  *(float4*)(out + (size_t)t * H_DIM + h) = o;
}

extern "C" void kernel_launch(void* const* d_in, const int* in_sizes, int n_in,
                              void* d_out, int out_size, void* d_ws, size_t ws_size,
                              hipStream_t stream) {
  const float* x  = (const float*)d_in[0];
  const float* gw = (const float*)d_in[1];
  const float* wg = (const float*)d_in[2];
  const float* wu = (const float*)d_in[3];
  const float* wd = (const float*)d_in[4];
  float* out = (float*)d_out;

  unsigned short* Xe = (unsigned short*)d_ws;
  unsigned short* Aw = Xe + (size_t)MCAP * H_DIM;
  unsigned short* Y  = Aw + (size_t)MCAP * F_DIM;
  Meta* m = (Meta*)(Y + (size_t)MCAP * H_DIM);
  uintptr_t wtp = ((uintptr_t)(m + 1) + 255) & ~(uintptr_t)255;
  unsigned short* WtG = (unsigned short*)wtp;
  const size_t WSZ = (size_t)N_EXP * H_DIM * F_DIM;   // elements per weight tensor
  unsigned short* WtU = WtG + WSZ;
  unsigned short* WtD = WtU + WSZ;
  size_t need = (size_t)((char*)(WtD + WSZ) - (char*)d_ws);
  bool big = ws_size >= need;

  k_init<<<1, 64, 0, stream>>>(m);
  k_router<<<T_TOK, 64, 0, stream>>>(x, gw, m);
  k_scan<<<1, 64, 0, stream>>>(m);
  k_assign<<<T_TOK / 256, 256, 0, stream>>>(m);
  k_gather<<<MCAP, 256, 0, stream>>>(x, Xe, m);

  if (big) {
    k_prep<<<dim3(F_DIM / 64, N_EXP, 1), 256, 0, stream>>>(wg, WtG, H_DIM, F_DIM / 64, F_DIM);
    k_prep<<<dim3(F_DIM / 64, N_EXP, 1), 256, 0, stream>>>(wu, WtU, H_DIM, F_DIM / 64, F_DIM);
    k_prep<<<dim3(H_DIM / 64, N_EXP, 4), 256, 0, stream>>>(wd, WtD, F_DIM, H_DIM / 64, H_DIM);
    k_gemm_dual2<<<dim3(F_DIM / BN, MCAP / BM), 256, 0, stream>>>(Xe, WtG, WtU, Aw, m);
    k_gemm_down2<<<dim3(H_DIM / BN, MCAP / BM), 256, 0, stream>>>(Aw, WtD, Y, m);
  } else {
    k_gemm_dual_fb<<<dim3(F_DIM / BN, MCAP / BM), 256, 0, stream>>>(Xe, wg, wu, Aw, m);
    k_gemm_down_fb<<<dim3(H_DIM / BN, MCAP / BM), 256, 0, stream>>>(Aw, wd, Y, m);
  }
  k_combine<<<T_TOK, 256, 0, stream>>>(Y, m, out);
}

// Round 3
// 697.459 us; speedup vs baseline: 1.0023x; 1.0023x over previous
//
#include <hip/hip_runtime.h>
#include <hip/hip_bf16.h>
#include <cstdint>

// MoE SwiGLU MLP, routed top-2. Round 3: register-transpose weight prep
// (no LDS, coalesced dwordx4 stores), m97-style GEMMs with global_load_lds,
// occupancy bumped to 4 waves/EU.

typedef short short8 __attribute__((ext_vector_type(8)));
typedef float floatx4 __attribute__((ext_vector_type(4)));

#define H_DIM 1024
#define F_DIM 4096
#define N_EXP 8
#define T_TOK 2048
#define MCAP  5120

#define BM 128
#define BN 64
#define BK 32
#define LDT 40   // fallback-path LDS pitch

struct Meta {
  int cnt[N_EXP];
  int cursor[N_EXP];
  int poff[N_EXP + 1];
  int pad0;
  int pair_token[MCAP];
  float pair_w[MCAP];
  int token_pair[2 * T_TOK];
  int tok_e[2 * T_TOK];
  float tok_w[2 * T_TOK];
};

__device__ __forceinline__ unsigned short f2b(float f) {
  unsigned int u = __float_as_uint(f);
  u = (u + 0x7fffu + ((u >> 16) & 1u)) >> 16;   // RNE
  return (unsigned short)u;
}
__device__ __forceinline__ float b2f(unsigned short h) {
  return __uint_as_float(((unsigned int)h) << 16);
}

// async global->LDS, 16B per lane; base wave-uniform, lands at base+lane*16.
__device__ __forceinline__ void gll16(const void* g, void* l) {
  __builtin_amdgcn_global_load_lds(
      (const __attribute__((address_space(1))) unsigned int*)g,
      (__attribute__((address_space(3))) unsigned int*)l, 16, 0, 0);
}

__global__ void k_init(Meta* __restrict__ m) {
  int i = threadIdx.x;
  if (i < N_EXP) { m->cnt[i] = 0; m->cursor[i] = 0; }
}

__global__ __launch_bounds__(64)
void k_router(const float* __restrict__ x, const float* __restrict__ gw,
              Meta* __restrict__ m) {
  int t = blockIdx.x;
  int lane = threadIdx.x;
  const float* xr = x + (size_t)t * H_DIM;
  float acc[N_EXP];
#pragma unroll
  for (int e = 0; e < N_EXP; ++e) acc[e] = 0.f;
  for (int i = 0; i < H_DIM / 64; ++i) {
    int h = i * 64 + lane;
    float xv = xr[h];
    const float* g = gw + (size_t)h * N_EXP;
#pragma unroll
    for (int e = 0; e < N_EXP; ++e) acc[e] += xv * g[e];
  }
#pragma unroll
  for (int e = 0; e < N_EXP; ++e) {
    float v = acc[e];
    for (int off = 32; off; off >>= 1) v += __shfl_xor(v, off, 64);
    acc[e] = v;
  }
  if (lane == 0) {
    float mx = acc[0];
    for (int e = 1; e < N_EXP; ++e) mx = fmaxf(mx, acc[e]);
    float p[N_EXP];
    float s = 0.f;
    for (int e = 0; e < N_EXP; ++e) { p[e] = __expf(acc[e] - mx); s += p[e]; }
    float inv = 1.f / s;
    for (int e = 0; e < N_EXP; ++e) p[e] *= inv;
    int i1 = 0;
    for (int e = 1; e < N_EXP; ++e) if (p[e] > p[i1]) i1 = e;
    int i2 = (i1 == 0) ? 1 : 0;
    for (int e = 0; e < N_EXP; ++e) if (e != i1 && p[e] > p[i2]) i2 = e;
    float w1 = 1.f / (1.f + __expf(p[i2] - p[i1]));  // softmax of top-2 probs
    m->tok_e[2 * t] = i1;     m->tok_e[2 * t + 1] = i2;
    m->tok_w[2 * t] = w1;     m->tok_w[2 * t + 1] = 1.f - w1;
    atomicAdd(&m->cnt[i1], 1);
    atomicAdd(&m->cnt[i2], 1);
  }
}

__global__ void k_scan(Meta* __restrict__ m) {
  if (threadIdx.x == 0 && blockIdx.x == 0) {
    int o = 0;
    for (int e = 0; e < N_EXP; ++e) {
      m->poff[e] = o;
      o += ((m->cnt[e] + BM - 1) / BM) * BM;
    }
    m->poff[N_EXP] = o;
  }
}

__global__ void k_assign(Meta* __restrict__ m) {
  int t = blockIdx.x * blockDim.x + threadIdx.x;
  if (t >= T_TOK) return;
  for (int k = 0; k < 2; ++k) {
    int e = m->tok_e[2 * t + k];
    int idx = atomicAdd(&m->cursor[e], 1);
    int p = m->poff[e] + idx;
    m->pair_token[p] = t;
    m->pair_w[p] = m->tok_w[2 * t + k];
    m->token_pair[2 * t + k] = p;
  }
}

__global__ __launch_bounds__(256)
void k_gather(const float* __restrict__ x, unsigned short* __restrict__ Xe,
              const Meta* __restrict__ m) {
  int r = blockIdx.x;
  if (r >= m->poff[N_EXP]) return;
  int e = 0;
#pragma unroll
  for (int i = 1; i < N_EXP; ++i) if (r >= m->poff[i]) e = i;
  bool real = (r - m->poff[e]) < m->cnt[e];
  int h = threadIdx.x * 4;
  ushort4 sv = {0, 0, 0, 0};
  if (real) {
    int t = m->pair_token[r];
    float4 f = *(const float4*)(x + (size_t)t * H_DIM + h);
    sv.x = f2b(f.x); sv.y = f2b(f.y); sv.z = f2b(f.z); sv.w = f2b(f.w);
  }
  *(ushort4*)(Xe + (size_t)r * H_DIM + h) = sv;
}

// ---- prep v2: fp32 [e][K][N] -> bf16 tiled [e][nt][kb][64n x 32k], register transpose ----
// lane = dn*4 + k8 : thread loads 8 stride-N dwords (rows k8*8..k8*8+7, col n),
// packs to one 16B chunk at image offset tid*8 -> fully coalesced dwordx4 store.
__global__ __launch_bounds__(256, 4)
void k_prep2(const float* __restrict__ W, unsigned short* __restrict__ Wt,
             int K, int NT, int N, int KB_PER) {
  int e = blockIdx.y, nt = blockIdx.x;
  int t = threadIdx.x;
  int wid = t >> 6, lane = t & 63;
  int dn = lane >> 2, k8 = lane & 3;
  int n = wid * 16 + dn;
  int KB = K >> 5;
  int kb0 = blockIdx.z * KB_PER;
  for (int i = 0; i < KB_PER; ++i) {
    int kb = kb0 + i;
    const float* src = W + ((size_t)e * K + (size_t)kb * 32 + k8 * 8) * N
                         + (size_t)nt * 64 + n;
    float v[8];
#pragma unroll
    for (int j = 0; j < 8; ++j) v[j] = src[(size_t)j * N];
    short8 o;
#pragma unroll
    for (int j = 0; j < 8; ++j) o[j] = (short)f2b(v[j]);
    size_t dst = (((size_t)e * NT + nt) * KB + kb) * 2048 + (size_t)t * 8;
    *(short8*)&Wt[dst] = o;
  }
}

// ---------------- GEMMs: global_load_lds staging, bf16 tiled B ----------------
__global__ __launch_bounds__(256, 4)
void k_gemm_dual2(const unsigned short* __restrict__ Xe,
                  const unsigned short* __restrict__ WtG,
                  const unsigned short* __restrict__ WtU,
                  unsigned short* __restrict__ Aw,
                  const Meta* __restrict__ m) {
  __shared__ __align__(16) unsigned short As[BM * 32];
  __shared__ __align__(16) unsigned short Bg[BN * 32];
  __shared__ __align__(16) unsigned short Bu[BN * 32];
  int tileM = blockIdx.y * BM;
  if (tileM >= m->poff[N_EXP]) return;
  int e = 0;
#pragma unroll
  for (int i = 1; i < N_EXP; ++i) if (tileM >= m->poff[i]) e = i;
  int nt = blockIdx.x;
  int n0 = nt * BN;

  int tid = threadIdx.x;
  int lane = tid & 63;
  int wid = tid >> 6;
  int wm = (wid & 1) * 64;
  int wn = (wid >> 1) * 32;
  int lm = lane & 15;
  int quad = lane >> 4;

  floatx4 accG[4][2] = {};
  floatx4 accU[4][2] = {};

  int c0 = wid * 128 + lane;
  int c1 = c0 + 64;
  int bc = wid * 64 + lane;

  for (int k0 = 0; k0 < H_DIM; k0 += BK) {
    int kb = k0 >> 5;
    size_t btile = (((size_t)e * (F_DIM / 64) + nt) * (H_DIM / 32) + kb) * 2048;
    gll16(Xe + (size_t)(tileM + (c0 >> 2)) * H_DIM + k0 + (c0 & 3) * 8, &As[wid * 1024]);
    gll16(Xe + (size_t)(tileM + (c1 >> 2)) * H_DIM + k0 + (c1 & 3) * 8, &As[wid * 1024 + 512]);
    gll16(WtG + btile + (size_t)bc * 8, &Bg[wid * 512]);
    gll16(WtU + btile + (size_t)bc * 8, &Bu[wid * 512]);
    __syncthreads();
    short8 a[4];
#pragma unroll
    for (int fm = 0; fm < 4; ++fm)
      a[fm] = *(const short8*)&As[(wm + fm * 16 + lm) * 32 + quad * 8];
#pragma unroll
    for (int fn = 0; fn < 2; ++fn) {
      short8 bg = *(const short8*)&Bg[(wn + fn * 16 + lm) * 32 + quad * 8];
      short8 bu = *(const short8*)&Bu[(wn + fn * 16 + lm) * 32 + quad * 8];
#pragma unroll
      for (int fm = 0; fm < 4; ++fm) {
        accG[fm][fn] = __builtin_amdgcn_mfma_f32_16x16x32_bf16(a[fm], bg, accG[fm][fn], 0, 0, 0);
        accU[fm][fn] = __builtin_amdgcn_mfma_f32_16x16x32_bf16(a[fm], bu, accU[fm][fn], 0, 0, 0);
      }
    }
    __syncthreads();
  }
#pragma unroll
  for (int fm = 0; fm < 4; ++fm)
#pragma unroll
    for (int fn = 0; fn < 2; ++fn)
#pragma unroll
      for (int r = 0; r < 4; ++r) {
        int row = tileM + wm + fm * 16 + quad * 4 + r;
        int col = n0 + wn + fn * 16 + lm;
        float g = accG[fm][fn][r];
        float u = accU[fm][fn][r];
        float s = g / (1.f + __expf(-g));
        Aw[(size_t)row * F_DIM + col] = f2b(s * u);
      }
}

__global__ __launch_bounds__(256, 4)
void k_gemm_down2(const unsigned short* __restrict__ Aw,
                  const unsigned short* __restrict__ WtD,
                  unsigned short* __restrict__ Y,
                  const Meta* __restrict__ m) {
  __shared__ __align__(16) unsigned short As[BM * 32];
  __shared__ __align__(16) unsigned short Bs[BN * 32];
  int tileM = blockIdx.y * BM;
  if (tileM >= m->poff[N_EXP]) return;
  int e = 0;
#pragma unroll
  for (int i = 1; i < N_EXP; ++i) if (tileM >= m->poff[i]) e = i;
  int nt = blockIdx.x;
  int n0 = nt * BN;

  int tid = threadIdx.x;
  int lane = tid & 63;
  int wid = tid >> 6;
  int wm = (wid & 1) * 64;
  int wn = (wid >> 1) * 32;
  int lm = lane & 15;
  int quad = lane >> 4;

  floatx4 acc[4][2] = {};

  int c0 = wid * 128 + lane;
  int c1 = c0 + 64;
  int bc = wid * 64 + lane;

  for (int k0 = 0; k0 < F_DIM; k0 += BK) {
    int kb = k0 >> 5;
    size_t btile = (((size_t)e * (H_DIM / 64) + nt) * (F_DIM / 32) + kb) * 2048;
    gll16(Aw + (size_t)(tileM + (c0 >> 2)) * F_DIM + k0 + (c0 & 3) * 8, &As[wid * 1024]);
    gll16(Aw + (size_t)(tileM + (c1 >> 2)) * F_DIM + k0 + (c1 & 3) * 8, &As[wid * 1024 + 512]);
    gll16(WtD + btile + (size_t)bc * 8, &Bs[wid * 512]);
    __syncthreads();
    short8 a[4];
#pragma unroll
    for (int fm = 0; fm < 4; ++fm)
      a[fm] = *(const short8*)&As[(wm + fm * 16 + lm) * 32 + quad * 8];
#pragma unroll
    for (int fn = 0; fn < 2; ++fn) {
      short8 b = *(const short8*)&Bs[(wn + fn * 16 + lm) * 32 + quad * 8];
#pragma unroll
      for (int fm = 0; fm < 4; ++fm)
        acc[fm][fn] = __builtin_amdgcn_mfma_f32_16x16x32_bf16(a[fm], b, acc[fm][fn], 0, 0, 0);
    }
    __syncthreads();
  }
#pragma unroll
  for (int fm = 0; fm < 4; ++fm)
#pragma unroll
    for (int fn = 0; fn < 2; ++fn)
#pragma unroll
      for (int r = 0; r < 4; ++r) {
        int row = tileM + wm + fm * 16 + quad * 4 + r;
        int col = n0 + wn + fn * 16 + lm;
        Y[(size_t)row * H_DIM + col] = f2b(acc[fm][fn][r]);
      }
}

// ---------------- fallback GEMMs (round-1, fp32 staging) ----------------
__global__ __launch_bounds__(256, 2)
void k_gemm_dual_fb(const unsigned short* __restrict__ Xe,
                    const float* __restrict__ w_gate,
                    const float* __restrict__ w_up,
                    unsigned short* __restrict__ Aw,
                    const Meta* __restrict__ m) {
  __shared__ unsigned short As[BM * LDT];
  __shared__ unsigned short Bg[BN * LDT];
  __shared__ unsigned short Bu[BN * LDT];
  int tileM = blockIdx.y * BM;
  if (tileM >= m->poff[N_EXP]) return;
  int e = 0;
#pragma unroll
  for (int i = 1; i < N_EXP; ++i) if (tileM >= m->poff[i]) e = i;
  int n0 = blockIdx.x * BN;
  const float* Wg = w_gate + (size_t)e * H_DIM * F_DIM;
  const float* Wu = w_up   + (size_t)e * H_DIM * F_DIM;
  int tid = threadIdx.x;
  int lane = tid & 63;
  int wid = tid >> 6;
  int wm = (wid & 1) * 64;
  int wn = (wid >> 1) * 32;
  int lm = lane & 15;
  int quad = lane >> 4;
  floatx4 accG[4][2] = {};
  floatx4 accU[4][2] = {};
  for (int k0 = 0; k0 < H_DIM; k0 += BK) {
    {
      int c = tid;
#pragma unroll
      for (int it = 0; it < 2; ++it, c += 256) {
        int row = c >> 2, kp = c & 3;
        *(uint4*)&As[row * LDT + kp * 8] =
            *(const uint4*)(Xe + (size_t)(tileM + row) * H_DIM + k0 + kp * 8);
      }
    }
    {
      int nn = tid & 63;
      int kh = tid >> 6;
      const float* sg = Wg + (size_t)(k0 + kh * 8) * F_DIM + n0 + nn;
      const float* su = Wu + (size_t)(k0 + kh * 8) * F_DIM + n0 + nn;
      short8 vg, vu;
#pragma unroll
      for (int j = 0; j < 8; ++j) {
        vg[j] = (short)f2b(sg[(size_t)j * F_DIM]);
        vu[j] = (short)f2b(su[(size_t)j * F_DIM]);
      }
      *(short8*)&Bg[nn * LDT + kh * 8] = vg;
      *(short8*)&Bu[nn * LDT + kh * 8] = vu;
    }
    __syncthreads();
    short8 a[4];
#pragma unroll
    for (int fm = 0; fm < 4; ++fm)
      a[fm] = *(const short8*)&As[(wm + fm * 16 + lm) * LDT + quad * 8];
#pragma unroll
    for (int fn = 0; fn < 2; ++fn) {
      short8 bg = *(const short8*)&Bg[(wn + fn * 16 + lm) * LDT + quad * 8];
      short8 bu = *(const short8*)&Bu[(wn + fn * 16 + lm) * LDT + quad * 8];
#pragma unroll
      for (int fm = 0; fm < 4; ++fm) {
        accG[fm][fn] = __builtin_amdgcn_mfma_f32_16x16x32_bf16(a[fm], bg, accG[fm][fn], 0, 0, 0);
        accU[fm][fn] = __builtin_amdgcn_mfma_f32_16x16x32_bf16(a[fm], bu, accU[fm][fn], 0, 0, 0);
      }
    }
    __syncthreads();
  }
#pragma unroll
  for (int fm = 0; fm < 4; ++fm)
#pragma unroll
    for (int fn = 0; fn < 2; ++fn)
#pragma unroll
      for (int r = 0; r < 4; ++r) {
        int row = tileM + wm + fm * 16 + quad * 4 + r;
        int col = n0 + wn + fn * 16 + lm;
        float g = accG[fm][fn][r];
        float u = accU[fm][fn][r];
        float s = g / (1.f + __expf(-g));
        Aw[(size_t)row * F_DIM + col] = f2b(s * u);
      }
}

__global__ __launch_bounds__(256, 2)
void k_gemm_down_fb(const unsigned short* __restrict__ Aw,
                    const float* __restrict__ w_down,
                    unsigned short* __restrict__ Y,
                    const Meta* __restrict__ m) {
  __shared__ unsigned short As[BM * LDT];
  __shared__ unsigned short Bs[BN * LDT];
  int tileM = blockIdx.y * BM;
  if (tileM >= m->poff[N_EXP]) return;
  int e = 0;
#pragma unroll
  for (int i = 1; i < N_EXP; ++i) if (tileM >= m->poff[i]) e = i;
  int n0 = blockIdx.x * BN;
  const float* W = w_down + (size_t)e * F_DIM * H_DIM;
  int tid = threadIdx.x;
  int lane = tid & 63;
  int wid = tid >> 6;
  int wm = (wid & 1) * 64;
  int wn = (wid >> 1) * 32;
  int lm = lane & 15;
  int quad = lane >> 4;
  floatx4 acc[4][2] = {};
  for (int k0 = 0; k0 < F_DIM; k0 += BK) {
    {
      int c = tid;
#pragma unroll
      for (int it = 0; it < 2; ++it, c += 256) {
        int row = c >> 2, kp = c & 3;
        *(uint4*)&As[row * LDT + kp * 8] =
            *(const uint4*)(Aw + (size_t)(tileM + row) * F_DIM + k0 + kp * 8);
      }
    }
    {
      int nn = tid & 63;
      int kh = tid >> 6;
      const float* s = W + (size_t)(k0 + kh * 8) * H_DIM + n0 + nn;
      short8 v;
#pragma unroll
      for (int j = 0; j < 8; ++j) v[j] = (short)f2b(s[(size_t)j * H_DIM]);
      *(short8*)&Bs[nn * LDT + kh * 8] = v;
    }
    __syncthreads();
    short8 a[4];
#pragma unroll
    for (int fm = 0; fm < 4; ++fm)
      a[fm] = *(const short8*)&As[(wm + fm * 16 + lm) * LDT + quad * 8];
#pragma unroll
    for (int fn = 0; fn < 2; ++fn) {
      short8 b = *(const short8*)&Bs[(wn + fn * 16 + lm) * LDT + quad * 8];
#pragma unroll
      for (int fm = 0; fm < 4; ++fm)
        acc[fm][fn] = __builtin_amdgcn_mfma_f32_16x16x32_bf16(a[fm], b, acc[fm][fn], 0, 0, 0);
    }
    __syncthreads();
  }
#pragma unroll
  for (int fm = 0; fm < 4; ++fm)
#pragma unroll
    for (int fn = 0; fn < 2; ++fn)
#pragma unroll
      for (int r = 0; r < 4; ++r) {
        int row = tileM + wm + fm * 16 + quad * 4 + r;
        int col = n0 + wn + fn * 16 + lm;
        Y[(size_t)row * H_DIM + col] = f2b(acc[fm][fn][r]);
      }
}

__global__ __launch_bounds__(256)
void k_combine(const unsigned short* __restrict__ Y, const Meta* __restrict__ m,
               float* __restrict__ out) {
  int t = blockIdx.x;
  int h = threadIdx.x * 4;
  int p0 = m->token_pair[2 * t];
  int p1 = m->token_pair[2 * t + 1];
  float w0 = m->pair_w[p0];
  float w1 = m->pair_w[p1];
  ushort4 y0 = *(const ushort4*)(Y + (size_t)p0 * H_DIM + h);
  ushort4 y1 = *(const ushort4*)(Y + (size_t)p1 * H_DIM + h);
  float4 o;
  o.x = w0 * b2f(y0.x) + w1 * b2f(y1.x);
  o.y = w0 * b2f(y0.y) + w1 * b2f(y1.y);
  o.z = w0 * b2f(y0.z) + w1 * b2f(y1.z);
  o.w = w0 * b2f(y0.w) + w1 * b2f(y1.w);
  *(float4*)(out + (size_t)t * H_DIM + h) = o;
}

extern "C" void kernel_launch(void* const* d_in, const int* in_sizes, int n_in,
                              void* d_out, int out_size, void* d_ws, size_t ws_size,
                              hipStream_t stream) {
  const float* x  = (const float*)d_in[0];
  const float* gw = (const float*)d_in[1];
  const float* wg = (const float*)d_in[2];
  const float* wu = (const float*)d_in[3];
  const float* wd = (const float*)d_in[4];
  float* out = (float*)d_out;

  unsigned short* Xe = (unsigned short*)d_ws;
  unsigned short* Aw = Xe + (size_t)MCAP * H_DIM;
  unsigned short* Y  = Aw + (size_t)MCAP * F_DIM;
  Meta* m = (Meta*)(Y + (size_t)MCAP * H_DIM);
  uintptr_t wtp = ((uintptr_t)(m + 1) + 255) & ~(uintptr_t)255;
  unsigned short* WtG = (unsigned short*)wtp;
  const size_t WSZ = (size_t)N_EXP * H_DIM * F_DIM;
  unsigned short* WtU = WtG + WSZ;
  unsigned short* WtD = WtU + WSZ;
  size_t need = (size_t)((char*)(WtD + WSZ) - (char*)d_ws);
  bool big = ws_size >= need;

  k_init<<<1, 64, 0, stream>>>(m);
  k_router<<<T_TOK, 64, 0, stream>>>(x, gw, m);
  k_scan<<<1, 64, 0, stream>>>(m);
  k_assign<<<T_TOK / 256, 256, 0, stream>>>(m);
  k_gather<<<MCAP, 256, 0, stream>>>(x, Xe, m);

  if (big) {
    // wg/wu: K=1024 (KB=32), N=4096 (NT=64); wd: K=4096 (KB=128), N=1024 (NT=16)
    k_prep2<<<dim3(F_DIM / 64, N_EXP, 8), 256, 0, stream>>>(wg, WtG, H_DIM, F_DIM / 64, F_DIM, 4);
    k_prep2<<<dim3(F_DIM / 64, N_EXP, 8), 256, 0, stream>>>(wu, WtU, H_DIM, F_DIM / 64, F_DIM, 4);
    k_prep2<<<dim3(H_DIM / 64, N_EXP, 32), 256, 0, stream>>>(wd, WtD, F_DIM, H_DIM / 64, H_DIM, 4);
    k_gemm_dual2<<<dim3(F_DIM / BN, MCAP / BM), 256, 0, stream>>>(Xe, WtG, WtU, Aw, m);
    k_gemm_down2<<<dim3(H_DIM / BN, MCAP / BM), 256, 0, stream>>>(Aw, WtD, Y, m);
  } else {
    k_gemm_dual_fb<<<dim3(F_DIM / BN, MCAP / BM), 256, 0, stream>>>(Xe, wg, wu, Aw, m);
    k_gemm_down_fb<<<dim3(H_DIM / BN, MCAP / BM), 256, 0, stream>>>(Aw, wd, Y, m);
  }
  k_combine<<<T_TOK, 256, 0, stream>>>(Y, m, out);
}

// Round 4
// 629.541 us; speedup vs baseline: 1.1104x; 1.1079x over previous
//
#include <hip/hip_runtime.h>
#include <hip/hip_bf16.h>
#include <cstdint>

// MoE SwiGLU MLP, routed top-2. Round 4: no global atomics (single-block
// plan kernel), merged preps, 8 dispatches total. GEMMs unchanged
// (m97-style global_load_lds, bf16 MFMA 16x16x32).

typedef short short8 __attribute__((ext_vector_type(8)));
typedef float floatx4 __attribute__((ext_vector_type(4)));

#define H_DIM 1024
#define F_DIM 4096
#define N_EXP 8
#define T_TOK 2048
#define MCAP  5120

#define BM 128
#define BN 64
#define BK 32

struct Meta {
  int cnt[N_EXP];
  int poff[N_EXP + 1];
  int pair_token[MCAP];
  float pair_w[MCAP];
  int token_pair[2 * T_TOK];
  int tok_e[2 * T_TOK];
  float tok_w[2 * T_TOK];
};

__device__ __forceinline__ unsigned short f2b(float f) {
  unsigned int u = __float_as_uint(f);
  u = (u + 0x7fffu + ((u >> 16) & 1u)) >> 16;   // RNE
  return (unsigned short)u;
}
__device__ __forceinline__ float b2f(unsigned short h) {
  return __uint_as_float(((unsigned int)h) << 16);
}

// async global->LDS, 16B per lane; base wave-uniform, lands at base+lane*16.
__device__ __forceinline__ void gll16(const void* g, void* l) {
  __builtin_amdgcn_global_load_lds(
      (const __attribute__((address_space(1))) unsigned int*)g,
      (__attribute__((address_space(3))) unsigned int*)l, 16, 0, 0);
}

// Router: 4 waves/block, one wave per token. NO atomics — just writes (e,w).
__global__ __launch_bounds__(256)
void k_router(const float* __restrict__ x, const float* __restrict__ gw,
              Meta* __restrict__ m) {
  int wave = threadIdx.x >> 6, lane = threadIdx.x & 63;
  int t = blockIdx.x * 4 + wave;
  const float* xr = x + (size_t)t * H_DIM;
  float acc[N_EXP];
#pragma unroll
  for (int e = 0; e < N_EXP; ++e) acc[e] = 0.f;
#pragma unroll 4
  for (int i = 0; i < H_DIM / 64; ++i) {
    int h = i * 64 + lane;
    float xv = xr[h];
    const float* g = gw + (size_t)h * N_EXP;
    float4 g0 = *(const float4*)g;
    float4 g1 = *(const float4*)(g + 4);
    acc[0] += xv * g0.x; acc[1] += xv * g0.y;
    acc[2] += xv * g0.z; acc[3] += xv * g0.w;
    acc[4] += xv * g1.x; acc[5] += xv * g1.y;
    acc[6] += xv * g1.z; acc[7] += xv * g1.w;
  }
#pragma unroll
  for (int e = 0; e < N_EXP; ++e) {
    float v = acc[e];
    for (int off = 32; off; off >>= 1) v += __shfl_xor(v, off, 64);
    acc[e] = v;
  }
  if (lane == 0) {
    float mx = acc[0];
    for (int e = 1; e < N_EXP; ++e) mx = fmaxf(mx, acc[e]);
    float p[N_EXP];
    float s = 0.f;
    for (int e = 0; e < N_EXP; ++e) { p[e] = __expf(acc[e] - mx); s += p[e]; }
    float inv = 1.f / s;
    for (int e = 0; e < N_EXP; ++e) p[e] *= inv;
    int i1 = 0;
    for (int e = 1; e < N_EXP; ++e) if (p[e] > p[i1]) i1 = e;
    int i2 = (i1 == 0) ? 1 : 0;
    for (int e = 0; e < N_EXP; ++e) if (e != i1 && p[e] > p[i2]) i2 = e;
    float w1 = 1.f / (1.f + __expf(p[i2] - p[i1]));  // softmax of top-2 probs
    m->tok_e[2 * t] = i1;     m->tok_e[2 * t + 1] = i2;
    m->tok_w[2 * t] = w1;     m->tok_w[2 * t + 1] = 1.f - w1;
  }
}

// Single block: histogram (LDS atomics) -> 128-aligned offsets -> slot assign.
// Replaces k_init + k_scan + k_assign; no global atomics anywhere.
__global__ __launch_bounds__(256)
void k_plan(Meta* __restrict__ m) {
  __shared__ int hist[N_EXP], cur[N_EXP], off[N_EXP + 1];
  int t = threadIdx.x;
  if (t < N_EXP) { hist[t] = 0; cur[t] = 0; }
  __syncthreads();
  for (int i = t; i < 2 * T_TOK; i += 256) atomicAdd(&hist[m->tok_e[i]], 1);
  __syncthreads();
  if (t == 0) {
    int o = 0;
    for (int e = 0; e < N_EXP; ++e) {
      off[e] = o; m->poff[e] = o; m->cnt[e] = hist[e];
      o += ((hist[e] + BM - 1) / BM) * BM;
    }
    off[N_EXP] = o; m->poff[N_EXP] = o;
  }
  __syncthreads();
  for (int i = t; i < 2 * T_TOK; i += 256) {
    int e = m->tok_e[i];
    int idx = atomicAdd(&cur[e], 1);
    int p = off[e] + idx;
    m->pair_token[p] = i >> 1;
    m->pair_w[p] = m->tok_w[i];
    m->token_pair[i] = p;
  }
}

__global__ __launch_bounds__(256)
void k_gather(const float* __restrict__ x, unsigned short* __restrict__ Xe,
              const Meta* __restrict__ m) {
  int r = blockIdx.x;
  if (r >= m->poff[N_EXP]) return;
  int e = 0;
#pragma unroll
  for (int i = 1; i < N_EXP; ++i) if (r >= m->poff[i]) e = i;
  bool real = (r - m->poff[e]) < m->cnt[e];
  int h = threadIdx.x * 4;
  ushort4 sv = {0, 0, 0, 0};
  if (real) {
    int t = m->pair_token[r];
    float4 f = *(const float4*)(x + (size_t)t * H_DIM + h);
    sv.x = f2b(f.x); sv.y = f2b(f.y); sv.z = f2b(f.z); sv.w = f2b(f.w);
  }
  *(ushort4*)(Xe + (size_t)r * H_DIM + h) = sv;
}

// prep: fp32 [e][K][N] -> bf16 tiled [e][nt][kb][64n x 32k] (LDS image order).
// Register transpose: lane = dn*4+k8, coalesced dwordx4 stores.
// Merged gate+up version: blockIdx.z selects tensor half.
__global__ __launch_bounds__(256, 4)
void k_prep_gu(const float* __restrict__ wg, const float* __restrict__ wu,
               unsigned short* __restrict__ WtG, unsigned short* __restrict__ WtU) {
  const int K = H_DIM, N = F_DIM, NT = F_DIM / 64, KB = K >> 5;
  int zi = blockIdx.z;                 // 0..15
  const float* W = (zi < 8) ? wg : wu;
  unsigned short* Wt = (zi < 8) ? WtG : WtU;
  int e = blockIdx.y, nt = blockIdx.x;
  int t = threadIdx.x;
  int wid = t >> 6, lane = t & 63;
  int dn = lane >> 2, k8 = lane & 3;
  int n = wid * 16 + dn;
  int kb0 = (zi & 7) * 4;
#pragma unroll
  for (int i = 0; i < 4; ++i) {
    int kb = kb0 + i;
    const float* src = W + ((size_t)e * K + (size_t)kb * 32 + k8 * 8) * N
                         + (size_t)nt * 64 + n;
    float v[8];
#pragma unroll
    for (int j = 0; j < 8; ++j) v[j] = src[(size_t)j * N];
    short8 o;
#pragma unroll
    for (int j = 0; j < 8; ++j) o[j] = (short)f2b(v[j]);
    size_t dst = (((size_t)e * NT + nt) * KB + kb) * 2048 + (size_t)t * 8;
    *(short8*)&Wt[dst] = o;
  }
}

__global__ __launch_bounds__(256, 4)
void k_prep_d(const float* __restrict__ W, unsigned short* __restrict__ Wt) {
  const int K = F_DIM, N = H_DIM, NT = H_DIM / 64, KB = K >> 5;
  int e = blockIdx.y, nt = blockIdx.x;
  int t = threadIdx.x;
  int wid = t >> 6, lane = t & 63;
  int dn = lane >> 2, k8 = lane & 3;
  int n = wid * 16 + dn;
  int kb0 = blockIdx.z * 4;
#pragma unroll
  for (int i = 0; i < 4; ++i) {
    int kb = kb0 + i;
    const float* src = W + ((size_t)e * K + (size_t)kb * 32 + k8 * 8) * N
                         + (size_t)nt * 64 + n;
    float v[8];
#pragma unroll
    for (int j = 0; j < 8; ++j) v[j] = src[(size_t)j * N];
    short8 o;
#pragma unroll
    for (int j = 0; j < 8; ++j) o[j] = (short)f2b(v[j]);
    size_t dst = (((size_t)e * NT + nt) * KB + kb) * 2048 + (size_t)t * 8;
    *(short8*)&Wt[dst] = o;
  }
}

// ---------------- GEMMs: global_load_lds staging, bf16 tiled B ----------------
__global__ __launch_bounds__(256, 4)
void k_gemm_dual2(const unsigned short* __restrict__ Xe,
                  const unsigned short* __restrict__ WtG,
                  const unsigned short* __restrict__ WtU,
                  unsigned short* __restrict__ Aw,
                  const Meta* __restrict__ m) {
  __shared__ __align__(16) unsigned short As[BM * 32];
  __shared__ __align__(16) unsigned short Bg[BN * 32];
  __shared__ __align__(16) unsigned short Bu[BN * 32];
  int tileM = blockIdx.y * BM;
  if (tileM >= m->poff[N_EXP]) return;
  int e = 0;
#pragma unroll
  for (int i = 1; i < N_EXP; ++i) if (tileM >= m->poff[i]) e = i;
  int nt = blockIdx.x;
  int n0 = nt * BN;

  int tid = threadIdx.x;
  int lane = tid & 63;
  int wid = tid >> 6;
  int wm = (wid & 1) * 64;
  int wn = (wid >> 1) * 32;
  int lm = lane & 15;
  int quad = lane >> 4;

  floatx4 accG[4][2] = {};
  floatx4 accU[4][2] = {};

  int c0 = wid * 128 + lane;
  int c1 = c0 + 64;
  int bc = wid * 64 + lane;

  for (int k0 = 0; k0 < H_DIM; k0 += BK) {
    int kb = k0 >> 5;
    size_t btile = (((size_t)e * (F_DIM / 64) + nt) * (H_DIM / 32) + kb) * 2048;
    gll16(Xe + (size_t)(tileM + (c0 >> 2)) * H_DIM + k0 + (c0 & 3) * 8, &As[wid * 1024]);
    gll16(Xe + (size_t)(tileM + (c1 >> 2)) * H_DIM + k0 + (c1 & 3) * 8, &As[wid * 1024 + 512]);
    gll16(WtG + btile + (size_t)bc * 8, &Bg[wid * 512]);
    gll16(WtU + btile + (size_t)bc * 8, &Bu[wid * 512]);
    __syncthreads();
    short8 a[4];
#pragma unroll
    for (int fm = 0; fm < 4; ++fm)
      a[fm] = *(const short8*)&As[(wm + fm * 16 + lm) * 32 + quad * 8];
#pragma unroll
    for (int fn = 0; fn < 2; ++fn) {
      short8 bg = *(const short8*)&Bg[(wn + fn * 16 + lm) * 32 + quad * 8];
      short8 bu = *(const short8*)&Bu[(wn + fn * 16 + lm) * 32 + quad * 8];
#pragma unroll
      for (int fm = 0; fm < 4; ++fm) {
        accG[fm][fn] = __builtin_amdgcn_mfma_f32_16x16x32_bf16(a[fm], bg, accG[fm][fn], 0, 0, 0);
        accU[fm][fn] = __builtin_amdgcn_mfma_f32_16x16x32_bf16(a[fm], bu, accU[fm][fn], 0, 0, 0);
      }
    }
    __syncthreads();
  }
#pragma unroll
  for (int fm = 0; fm < 4; ++fm)
#pragma unroll
    for (int fn = 0; fn < 2; ++fn)
#pragma unroll
      for (int r = 0; r < 4; ++r) {
        int row = tileM + wm + fm * 16 + quad * 4 + r;
        int col = n0 + wn + fn * 16 + lm;
        float g = accG[fm][fn][r];
        float u = accU[fm][fn][r];
        float s = g / (1.f + __expf(-g));
        Aw[(size_t)row * F_DIM + col] = f2b(s * u);
      }
}

__global__ __launch_bounds__(256, 4)
void k_gemm_down2(const unsigned short* __restrict__ Aw,
                  const unsigned short* __restrict__ WtD,
                  unsigned short* __restrict__ Y,
                  const Meta* __restrict__ m) {
  __shared__ __align__(16) unsigned short As[BM * 32];
  __shared__ __align__(16) unsigned short Bs[BN * 32];
  int tileM = blockIdx.y * BM;
  if (tileM >= m->poff[N_EXP]) return;
  int e = 0;
#pragma unroll
  for (int i = 1; i < N_EXP; ++i) if (tileM >= m->poff[i]) e = i;
  int nt = blockIdx.x;
  int n0 = nt * BN;

  int tid = threadIdx.x;
  int lane = tid & 63;
  int wid = tid >> 6;
  int wm = (wid & 1) * 64;
  int wn = (wid >> 1) * 32;
  int lm = lane & 15;
  int quad = lane >> 4;

  floatx4 acc[4][2] = {};

  int c0 = wid * 128 + lane;
  int c1 = c0 + 64;
  int bc = wid * 64 + lane;

  for (int k0 = 0; k0 < F_DIM; k0 += BK) {
    int kb = k0 >> 5;
    size_t btile = (((size_t)e * (H_DIM / 64) + nt) * (F_DIM / 32) + kb) * 2048;
    gll16(Aw + (size_t)(tileM + (c0 >> 2)) * F_DIM + k0 + (c0 & 3) * 8, &As[wid * 1024]);
    gll16(Aw + (size_t)(tileM + (c1 >> 2)) * F_DIM + k0 + (c1 & 3) * 8, &As[wid * 1024 + 512]);
    gll16(WtD + btile + (size_t)bc * 8, &Bs[wid * 512]);
    __syncthreads();
    short8 a[4];
#pragma unroll
    for (int fm = 0; fm < 4; ++fm)
      a[fm] = *(const short8*)&As[(wm + fm * 16 + lm) * 32 + quad * 8];
#pragma unroll
    for (int fn = 0; fn < 2; ++fn) {
      short8 b = *(const short8*)&Bs[(wn + fn * 16 + lm) * 32 + quad * 8];
#pragma unroll
      for (int fm = 0; fm < 4; ++fm)
        acc[fm][fn] = __builtin_amdgcn_mfma_f32_16x16x32_bf16(a[fm], b, acc[fm][fn], 0, 0, 0);
    }
    __syncthreads();
  }
#pragma unroll
  for (int fm = 0; fm < 4; ++fm)
#pragma unroll
    for (int fn = 0; fn < 2; ++fn)
#pragma unroll
      for (int r = 0; r < 4; ++r) {
        int row = tileM + wm + fm * 16 + quad * 4 + r;
        int col = n0 + wn + fn * 16 + lm;
        Y[(size_t)row * H_DIM + col] = f2b(acc[fm][fn][r]);
      }
}

__global__ __launch_bounds__(256)
void k_combine(const unsigned short* __restrict__ Y, const Meta* __restrict__ m,
               float* __restrict__ out) {
  int t = blockIdx.x;
  int h = threadIdx.x * 4;
  int p0 = m->token_pair[2 * t];
  int p1 = m->token_pair[2 * t + 1];
  float w0 = m->pair_w[p0];
  float w1 = m->pair_w[p1];
  ushort4 y0 = *(const ushort4*)(Y + (size_t)p0 * H_DIM + h);
  ushort4 y1 = *(const ushort4*)(Y + (size_t)p1 * H_DIM + h);
  float4 o;
  o.x = w0 * b2f(y0.x) + w1 * b2f(y1.x);
  o.y = w0 * b2f(y0.y) + w1 * b2f(y1.y);
  o.z = w0 * b2f(y0.z) + w1 * b2f(y1.z);
  o.w = w0 * b2f(y0.w) + w1 * b2f(y1.w);
  *(float4*)(out + (size_t)t * H_DIM + h) = o;
}

extern "C" void kernel_launch(void* const* d_in, const int* in_sizes, int n_in,
                              void* d_out, int out_size, void* d_ws, size_t ws_size,
                              hipStream_t stream) {
  const float* x  = (const float*)d_in[0];
  const float* gw = (const float*)d_in[1];
  const float* wg = (const float*)d_in[2];
  const float* wu = (const float*)d_in[3];
  const float* wd = (const float*)d_in[4];
  float* out = (float*)d_out;

  unsigned short* Xe = (unsigned short*)d_ws;
  unsigned short* Aw = Xe + (size_t)MCAP * H_DIM;
  unsigned short* Y  = Aw + (size_t)MCAP * F_DIM;
  Meta* m = (Meta*)(Y + (size_t)MCAP * H_DIM);
  uintptr_t wtp = ((uintptr_t)(m + 1) + 255) & ~(uintptr_t)255;
  unsigned short* WtG = (unsigned short*)wtp;
  const size_t WSZ = (size_t)N_EXP * H_DIM * F_DIM;
  unsigned short* WtU = WtG + WSZ;
  unsigned short* WtD = WtU + WSZ;

  k_router<<<T_TOK / 4, 256, 0, stream>>>(x, gw, m);
  k_plan<<<1, 256, 0, stream>>>(m);
  k_gather<<<MCAP, 256, 0, stream>>>(x, Xe, m);
  k_prep_gu<<<dim3(F_DIM / 64, N_EXP, 16), 256, 0, stream>>>(wg, wu, WtG, WtU);
  k_prep_d<<<dim3(H_DIM / 64, N_EXP, 32), 256, 0, stream>>>(wd, WtD);
  k_gemm_dual2<<<dim3(F_DIM / BN, MCAP / BM), 256, 0, stream>>>(Xe, WtG, WtU, Aw, m);
  k_gemm_down2<<<dim3(H_DIM / BN, MCAP / BM), 256, 0, stream>>>(Aw, WtD, Y, m);
  k_combine<<<T_TOK, 256, 0, stream>>>(Y, m, out);
}